// Round 3
// baseline (1266.287 us; speedup 1.0000x reference)
//
#include <hip/hip_runtime.h>
#include <stdint.h>

#define TT 2048
#define DM 2048
#define NH 16
#define HD 128
#define FFN 8192
#define MR 4096   // B*T
#define EPSF 1.1920928955078125e-07f
#define NEGBIG (-1.0e30f)

typedef __attribute__((ext_vector_type(8))) short short8;
typedef __attribute__((ext_vector_type(4))) float f32x4;
typedef unsigned short u16;
typedef unsigned int u32;

__device__ __forceinline__ float bf2f(u32 u) {
    return __uint_as_float((u & 0xffffu) << 16);
}
__device__ __forceinline__ u16 f2bf(float f) {
    u32 x = __float_as_uint(f);
    return (u16)((x + 0x7fffu + ((x >> 16) & 1u)) >> 16);
}
__device__ __forceinline__ void load8f(const u16* p, float* v) {
    uint4 d = *(const uint4*)p;
    v[0] = bf2f(d.x); v[1] = bf2f(d.x >> 16);
    v[2] = bf2f(d.y); v[3] = bf2f(d.y >> 16);
    v[4] = bf2f(d.z); v[5] = bf2f(d.z >> 16);
    v[6] = bf2f(d.w); v[7] = bf2f(d.w >> 16);
}
__device__ __forceinline__ void load8f32(const float* p, float* v) {
    float4 a = *(const float4*)p, b = *(const float4*)(p + 4);
    v[0]=a.x; v[1]=a.y; v[2]=a.z; v[3]=a.w; v[4]=b.x; v[5]=b.y; v[6]=b.z; v[7]=b.w;
}
__device__ __forceinline__ void store8bf(u16* p, const float* v) {
    uint4 o;
    o.x = (u32)f2bf(v[0]) | ((u32)f2bf(v[1]) << 16);
    o.y = (u32)f2bf(v[2]) | ((u32)f2bf(v[3]) << 16);
    o.z = (u32)f2bf(v[4]) | ((u32)f2bf(v[5]) << 16);
    o.w = (u32)f2bf(v[6]) | ((u32)f2bf(v[7]) << 16);
    *(uint4*)p = o;
}
__device__ __forceinline__ uint4 cvt8_f32_bf16(const float* p) {
    float4 a = *(const float4*)p, b = *(const float4*)(p + 4);
    uint4 o;
    o.x = (u32)f2bf(a.x) | ((u32)f2bf(a.y) << 16);
    o.y = (u32)f2bf(a.z) | ((u32)f2bf(a.w) << 16);
    o.z = (u32)f2bf(b.x) | ((u32)f2bf(b.y) << 16);
    o.w = (u32)f2bf(b.z) | ((u32)f2bf(b.w) << 16);
    return o;
}

// ---------------- RMSNorm (f32 in, bf16 out): one block per row of 2048 ----------------
__global__ __launch_bounds__(256)
void rmsnorm_k(const float* __restrict__ X, const float* __restrict__ W, u16* __restrict__ O) {
    const int row = blockIdx.x, tid = threadIdx.x;
    float v[8];
    load8f32(X + (size_t)row * DM + tid * 8, v);
    float ssq = 0.f;
#pragma unroll
    for (int i = 0; i < 8; ++i) ssq += v[i] * v[i];
#pragma unroll
    for (int d = 1; d < 64; d <<= 1) ssq += __shfl_xor(ssq, d);
    __shared__ float red[4];
    if ((tid & 63) == 0) red[tid >> 6] = ssq;
    __syncthreads();
    ssq = red[0] + red[1] + red[2] + red[3];
    const float inv = rsqrtf(ssq * (1.f / DM) + EPSF);
    float wv[8], o[8];
    load8f32(W + tid * 8, wv);
#pragma unroll
    for (int i = 0; i < 8; ++i) o[i] = v[i] * inv * wv[i];
    store8bf(O + (size_t)row * DM + tid * 8, o);
}

// ---------------- GEMM C[M,N] = A[M,K](bf16) * Bw[N,K](f32)^T, fused epilogues ----------------
// EPI: 0=bf16 out, 1=relu^2 bf16 out, 2=+f32 residual -> f32 out, 3=+f32 residual -> f32 out
template<int EPI>
__global__ __launch_bounds__(256)
void gemm_bt(const u16* __restrict__ A, const float* __restrict__ Bw,
             const float* __restrict__ Res, void* __restrict__ Cp,
             int M, int N, int K) {
    __shared__ alignas(16) u16 As[128 * 32];
    __shared__ alignas(16) u16 Bs[128 * 32];
    const int tid = threadIdx.x;
    const int lane = tid & 63, w = tid >> 6;
    const int quad = lane >> 4, col = lane & 15;
    const int n0 = blockIdx.x * 128, m0 = blockIdx.y * 128;
    const int wm = (w >> 1) * 64, wn = (w & 1) * 64;

    // staging: 512 chunks of 8 elems per tile, 2 per thread; LDS slot s of row r holds
    // global chunk q = s ^ ((r>>1)&3)
    const int c0 = tid, c1 = tid + 256;
    const int ar0 = c0 >> 2, aq0 = (c0 & 3) ^ ((ar0 >> 1) & 3);
    const int ar1 = c1 >> 2, aq1 = (c1 & 3) ^ ((ar1 >> 1) & 3);
    const u16*   agp0 = A  + (size_t)(m0 + ar0) * K + aq0 * 8;
    const u16*   agp1 = A  + (size_t)(m0 + ar1) * K + aq1 * 8;
    const float* bgp0 = Bw + (size_t)(n0 + ar0) * K + aq0 * 8;
    const float* bgp1 = Bw + (size_t)(n0 + ar1) * K + aq1 * 8;
    u16* al0 = As + c0 * 8; u16* al1 = As + c1 * 8;
    u16* bl0 = Bs + c0 * 8; u16* bl1 = Bs + c1 * 8;

    int aoff[4], boff[4];
#pragma unroll
    for (int i = 0; i < 4; ++i) {
        int r = wm + i * 16 + col;
        aoff[i] = r * 32 + (quad ^ ((r >> 1) & 3)) * 8;
        r = wn + i * 16 + col;
        boff[i] = r * 32 + (quad ^ ((r >> 1) & 3)) * 8;
    }

    f32x4 acc[4][4];
#pragma unroll
    for (int i = 0; i < 4; ++i)
#pragma unroll
        for (int j = 0; j < 4; ++j) acc[i][j] = (f32x4){0.f, 0.f, 0.f, 0.f};

    for (int kt = 0; kt < K; kt += 32) {
        uint4 av0 = *(const uint4*)(agp0 + kt);
        uint4 av1 = *(const uint4*)(agp1 + kt);
        uint4 bv0 = cvt8_f32_bf16(bgp0 + kt);
        uint4 bv1 = cvt8_f32_bf16(bgp1 + kt);
        __syncthreads();
        *(uint4*)al0 = av0;
        *(uint4*)al1 = av1;
        *(uint4*)bl0 = bv0;
        *(uint4*)bl1 = bv1;
        __syncthreads();
        short8 af[4], bfr[4];
#pragma unroll
        for (int i = 0; i < 4; ++i) af[i] = *(const short8*)(As + aoff[i]);
#pragma unroll
        for (int i = 0; i < 4; ++i) bfr[i] = *(const short8*)(Bs + boff[i]);
#pragma unroll
        for (int mi = 0; mi < 4; ++mi)
#pragma unroll
            for (int ni = 0; ni < 4; ++ni)
                acc[mi][ni] = __builtin_amdgcn_mfma_f32_16x16x32_bf16(af[mi], bfr[ni], acc[mi][ni], 0, 0, 0);
    }

#pragma unroll
    for (int mi = 0; mi < 4; ++mi)
#pragma unroll
        for (int ni = 0; ni < 4; ++ni) {
            const int rbase = m0 + wm + mi * 16 + quad * 4;
            const int cc = n0 + wn + ni * 16 + col;
#pragma unroll
            for (int rr = 0; rr < 4; ++rr) {
                float v = acc[mi][ni][rr];
                size_t idx = (size_t)(rbase + rr) * N + cc;
                if (EPI == 0) ((u16*)Cp)[idx] = f2bf(v);
                else if (EPI == 1) { float t = fmaxf(v, 0.f); ((u16*)Cp)[idx] = f2bf(t * t); }
                else ((float*)Cp)[idx] = v + Res[idx];
            }
        }
}

// ---------------- RoPE + per-head RMSNorm on q,k; split v ----------------
__global__ __launch_bounds__(256)
void rope_split_k(const u16* __restrict__ QKV, const float* __restrict__ RC,
                  const float* __restrict__ QW, const float* __restrict__ KW,
                  u16* __restrict__ Qo, u16* __restrict__ Ko, u16* __restrict__ Vo) {
    const int row = blockIdx.x;                 // b*T + t
    const int t = row & (TT - 1), b = row >> 11;
    const int tid = threadIdx.x, h = tid >> 4, j = tid & 15;
    const size_t qb = (size_t)row * (3 * DM) + h * HD + j * 8;
    float q[8], k[8], cs[8], sn[8];
    load8f(QKV + qb, q);
    load8f(QKV + qb + DM, k);
    uint4 vv = *(const uint4*)(QKV + qb + 2 * DM);
    load8f32(RC + (size_t)t * HD + j * 8, cs);
    load8f32(RC + (size_t)(TT + t) * HD + j * 8, sn);
    float qr[8], kr[8];
#pragma unroll
    for (int p = 0; p < 4; ++p) {
        float c = cs[2 * p], s = sn[2 * p];
        qr[2*p]   = q[2*p]   * c - q[2*p+1] * s;
        qr[2*p+1] = q[2*p+1] * c + q[2*p]   * s;
        kr[2*p]   = k[2*p]   * c - k[2*p+1] * s;
        kr[2*p+1] = k[2*p+1] * c + k[2*p]   * s;
    }
    float sq = 0.f, sk = 0.f;
#pragma unroll
    for (int i = 0; i < 8; ++i) { sq += qr[i] * qr[i]; sk += kr[i] * kr[i]; }
#pragma unroll
    for (int d = 1; d < 16; d <<= 1) { sq += __shfl_xor(sq, d); sk += __shfl_xor(sk, d); }
    const float iq = rsqrtf(sq * (1.f / HD) + EPSF);
    const float ik = rsqrtf(sk * (1.f / HD) + EPSF);
    float qw[8], kw[8], oq[8], ok[8];
    load8f32(QW + j * 8, qw); load8f32(KW + j * 8, kw);
#pragma unroll
    for (int i = 0; i < 8; ++i) { oq[i] = qr[i] * iq * qw[i]; ok[i] = kr[i] * ik * kw[i]; }
    const size_t ob = ((size_t)(b * NH + h) * TT + t) * HD + j * 8;
    store8bf(Qo + ob, oq);
    store8bf(Ko + ob, ok);
    *(uint4*)(Vo + ob) = vv;
}

// ---------------- V transpose: [bh][T][128] -> [bh][128][T] ----------------
__global__ __launch_bounds__(256)
void transpose_v(const u16* __restrict__ V, u16* __restrict__ Vt) {
    __shared__ alignas(16) u16 tile[64][72];
    const int bh = blockIdx.z;
    const int t0 = blockIdx.x * 64, d0 = blockIdx.y * 64;
    const int tid = threadIdx.x;
#pragma unroll
    for (int i = 0; i < 2; ++i) {
        int c = i * 256 + tid;
        int r = c >> 3, cc = (c & 7) * 8;
        *(uint4*)(&tile[r][cc]) = *(const uint4*)(V + ((size_t)bh * TT + t0 + r) * HD + d0 + cc);
    }
    __syncthreads();
#pragma unroll
    for (int i = 0; i < 2; ++i) {
        int c = i * 256 + tid;
        int dc = c >> 3, rr = (c & 7) * 8;
        u16 tmp[8];
#pragma unroll
        for (int kk = 0; kk < 8; ++kk) tmp[kk] = tile[rr + kk][dc];
        uint4 o;
        o.x = (u32)tmp[0] | ((u32)tmp[1] << 16);
        o.y = (u32)tmp[2] | ((u32)tmp[3] << 16);
        o.z = (u32)tmp[4] | ((u32)tmp[5] << 16);
        o.w = (u32)tmp[6] | ((u32)tmp[7] << 16);
        *(uint4*)(Vt + ((size_t)bh * HD + d0 + dc) * TT + t0 + rr) = o;
    }
}

// ---------------- Causal flash attention, 64-query tile per block ----------------
__global__ __launch_bounds__(256)
void attn_k(const u16* __restrict__ Q, const u16* __restrict__ Kg,
            const u16* __restrict__ Vt, u16* __restrict__ O) {
    __shared__ alignas(16) u16 k_lds[64 * 128];
    __shared__ alignas(16) u16 v_lds[128 * 64];
    __shared__ alignas(16) u16 p_lds[4 * 16 * 72];
    const int qt = gridDim.x - 1 - blockIdx.x;   // long blocks first
    const int bh = blockIdx.y;
    const int tid = threadIdx.x, lane = tid & 63, w = tid >> 6;
    const int quad = lane >> 4, col = lane & 15;
    const int qbase = qt * 64;
    const int qrow = qbase + w * 16 + col;

    short8 qf[4];
    const u16* qp = Q + ((size_t)bh * TT + qrow) * HD;
#pragma unroll
    for (int s = 0; s < 4; ++s) qf[s] = *(const short8*)(qp + s * 32 + quad * 8);

    f32x4 oacc[8];
#pragma unroll
    for (int i = 0; i < 8; ++i) oacc[i] = (f32x4){0.f, 0.f, 0.f, 0.f};
    float mrow[4] = {NEGBIG, NEGBIG, NEGBIG, NEGBIG};
    float lrow[4] = {0.f, 0.f, 0.f, 0.f};
    const float scale = 0.08838834764831845f;   // 1/sqrt(128)

    for (int kt = 0; kt <= qt; ++kt) {
        const int kb = kt * 64;
        uint4 kreg[4], vreg[4];
#pragma unroll
        for (int i = 0; i < 4; ++i) {     // K tile: 64 rows x 16 chunks
            int lin = i * 256 + tid;
            int r = lin >> 4, sl = lin & 15;
            int gq = sl ^ (r & 15);
            kreg[i] = *(const uint4*)(Kg + ((size_t)bh * TT + kb + r) * HD + gq * 8);
        }
#pragma unroll
        for (int i = 0; i < 4; ++i) {     // Vt tile: 128 rows x 8 chunks
            int lin = i * 256 + tid;
            int r = lin >> 3, sl = lin & 7;
            int gq = sl ^ (r & 7);
            vreg[i] = *(const uint4*)(Vt + ((size_t)bh * HD + r) * TT + kb + gq * 8);
        }
        __syncthreads();
#pragma unroll
        for (int i = 0; i < 4; ++i) *(uint4*)(k_lds + (i * 256 + tid) * 8) = kreg[i];
#pragma unroll
        for (int i = 0; i < 4; ++i) *(uint4*)(v_lds + (i * 256 + tid) * 8) = vreg[i];
        __syncthreads();

        f32x4 sfr[4];
#pragma unroll
        for (int ni = 0; ni < 4; ++ni) sfr[ni] = (f32x4){0.f, 0.f, 0.f, 0.f};
#pragma unroll
        for (int ni = 0; ni < 4; ++ni) {
            const int r = ni * 16 + col;
#pragma unroll
            for (int s = 0; s < 4; ++s) {
                int sl = (s * 4 + quad) ^ (r & 15);
                short8 kf = *(const short8*)(k_lds + r * 128 + sl * 8);
                sfr[ni] = __builtin_amdgcn_mfma_f32_16x16x32_bf16(qf[s], kf, sfr[ni], 0, 0, 0);
            }
        }
        const bool diag = (kt == qt);
#pragma unroll
        for (int ni = 0; ni < 4; ++ni) {
            const int key = kb + ni * 16 + col;
#pragma unroll
            for (int rr = 0; rr < 4; ++rr) {
                float v = sfr[ni][rr] * scale;
                int qv = qbase + w * 16 + quad * 4 + rr;
                if (diag && key > qv) v = NEGBIG;
                sfr[ni][rr] = v;
            }
        }
        float mx[4];
#pragma unroll
        for (int rr = 0; rr < 4; ++rr)
            mx[rr] = fmaxf(fmaxf(sfr[0][rr], sfr[1][rr]), fmaxf(sfr[2][rr], sfr[3][rr]));
#pragma unroll
        for (int d = 1; d < 16; d <<= 1)
#pragma unroll
            for (int rr = 0; rr < 4; ++rr) mx[rr] = fmaxf(mx[rr], __shfl_xor(mx[rr], d));
        float alpha[4], rs[4];
#pragma unroll
        for (int rr = 0; rr < 4; ++rr) {
            float mn = fmaxf(mrow[rr], mx[rr]);
            alpha[rr] = __expf(mrow[rr] - mn);
            mrow[rr] = mn;
            rs[rr] = 0.f;
        }
#pragma unroll
        for (int ni = 0; ni < 4; ++ni)
#pragma unroll
            for (int rr = 0; rr < 4; ++rr) {
                float p = __expf(sfr[ni][rr] - mrow[rr]);
                sfr[ni][rr] = p;
                rs[rr] += p;
            }
#pragma unroll
        for (int d = 1; d < 16; d <<= 1)
#pragma unroll
            for (int rr = 0; rr < 4; ++rr) rs[rr] += __shfl_xor(rs[rr], d);
#pragma unroll
        for (int rr = 0; rr < 4; ++rr) lrow[rr] = lrow[rr] * alpha[rr] + rs[rr];
#pragma unroll
        for (int i = 0; i < 8; ++i)
#pragma unroll
            for (int rr = 0; rr < 4; ++rr) oacc[i][rr] *= alpha[rr];
        // P (C-layout) -> LDS -> A-layout
#pragma unroll
        for (int ni = 0; ni < 4; ++ni)
#pragma unroll
            for (int rr = 0; rr < 4; ++rr)
                p_lds[(w * 16 + quad * 4 + rr) * 72 + ni * 16 + col] = f2bf(sfr[ni][rr]);
#pragma unroll
        for (int ks = 0; ks < 2; ++ks) {
            short8 pa = *(const short8*)(p_lds + (w * 16 + col) * 72 + ks * 32 + quad * 8);
#pragma unroll
            for (int di = 0; di < 8; ++di) {
                int r = di * 16 + col;
                int sl = (ks * 4 + quad) ^ (r & 7);
                short8 vb = *(const short8*)(v_lds + r * 64 + sl * 8);
                oacc[di] = __builtin_amdgcn_mfma_f32_16x16x32_bf16(pa, vb, oacc[di], 0, 0, 0);
            }
        }
    }
    const int b = bh >> 4, h = bh & 15;
#pragma unroll
    for (int di = 0; di < 8; ++di)
#pragma unroll
        for (int rr = 0; rr < 4; ++rr) {
            int trow = qbase + w * 16 + quad * 4 + rr;
            float ov = oacc[di][rr] / lrow[rr];
            O[((size_t)(b * TT + trow)) * DM + h * HD + di * 16 + col] = f2bf(ov);
        }
}

extern "C" void kernel_launch(void* const* d_in, const int* in_sizes, int n_in,
                              void* d_out, int out_size, void* d_ws, size_t ws_size,
                              hipStream_t stream) {
    const float* x    = (const float*)d_in[0];
    const float* rc   = (const float*)d_in[1];
    const float* anw  = (const float*)d_in[2];
    const float* qkvw = (const float*)d_in[3];
    const float* qnw  = (const float*)d_in[4];
    const float* knw  = (const float*)d_in[5];
    const float* opw  = (const float*)d_in[6];
    const float* mnw  = (const float*)d_in[7];
    const float* miw  = (const float*)d_in[8];
    const float* mow  = (const float*)d_in[9];

    char* ws = (char*)d_ws;
    // Workspace plan (128 MiB peak, regions reused once dead):
    //  [0,16)    hbuf (h, then h2)                          bf16
    //  [16,64)   qkv (48); dead after rope -> aout [16,32) bf16, x2 f32 [32,64)
    //  [64,112)  qh|kh|vh ; dead after attn -> mbuf [64,128) bf16
    //  [112,128) vt (dead before mbuf is written)
    u16*   hbuf = (u16*)(ws);
    u16*   qkv  = (u16*)(ws + (16ll << 20));
    u16*   aout = (u16*)(ws + (16ll << 20));
    float* x2   = (float*)(ws + (32ll << 20));
    u16*   qh   = (u16*)(ws + (64ll << 20));
    u16*   kh   = (u16*)(ws + (80ll << 20));
    u16*   vh   = (u16*)(ws + (96ll << 20));
    u16*   mbuf = (u16*)(ws + (64ll << 20));
    u16*   vt   = (u16*)(ws + (112ll << 20));

    rmsnorm_k<<<MR, 256, 0, stream>>>(x, anw, hbuf);
    gemm_bt<0><<<dim3(48, 32), 256, 0, stream>>>(hbuf, qkvw, nullptr, qkv, MR, 3 * DM, DM);
    rope_split_k<<<MR, 256, 0, stream>>>(qkv, rc, qnw, knw, qh, kh, vh);
    transpose_v<<<dim3(32, 2, 32), 256, 0, stream>>>(vh, vt);
    attn_k<<<dim3(32, 32), 256, 0, stream>>>(qh, kh, vt, aout);
    gemm_bt<2><<<dim3(16, 32), 256, 0, stream>>>(aout, opw, x, x2, MR, DM, DM);
    rmsnorm_k<<<MR, 256, 0, stream>>>(x2, mnw, hbuf);
    gemm_bt<1><<<dim3(64, 32), 256, 0, stream>>>(hbuf, miw, nullptr, mbuf, MR, FFN, DM);
    gemm_bt<3><<<dim3(16, 32), 256, 0, stream>>>(mbuf, mow, x2, (float*)d_out, MR, DM, FFN);
}

// Round 4
// 1168.324 us; speedup vs baseline: 1.0838x; 1.0838x over previous
//
#include <hip/hip_runtime.h>
#include <stdint.h>

#define TT 2048
#define DM 2048
#define NH 16
#define HD 128
#define FFN 8192
#define MR 4096   // B*T
#define EPSF 1.1920928955078125e-07f
#define NEGBIG (-1.0e30f)

typedef __attribute__((ext_vector_type(8))) short short8;
typedef __attribute__((ext_vector_type(4))) float f32x4;
typedef unsigned short u16;
typedef unsigned int u32;

__device__ __forceinline__ float bf2f(u32 u) {
    return __uint_as_float((u & 0xffffu) << 16);
}
__device__ __forceinline__ u16 f2bf(float f) {
    u32 x = __float_as_uint(f);
    return (u16)((x + 0x7fffu + ((x >> 16) & 1u)) >> 16);
}
__device__ __forceinline__ void load8f(const u16* p, float* v) {
    uint4 d = *(const uint4*)p;
    v[0] = bf2f(d.x); v[1] = bf2f(d.x >> 16);
    v[2] = bf2f(d.y); v[3] = bf2f(d.y >> 16);
    v[4] = bf2f(d.z); v[5] = bf2f(d.z >> 16);
    v[6] = bf2f(d.w); v[7] = bf2f(d.w >> 16);
}
__device__ __forceinline__ void load8f32(const float* p, float* v) {
    float4 a = *(const float4*)p, b = *(const float4*)(p + 4);
    v[0]=a.x; v[1]=a.y; v[2]=a.z; v[3]=a.w; v[4]=b.x; v[5]=b.y; v[6]=b.z; v[7]=b.w;
}
__device__ __forceinline__ void store8bf(u16* p, const float* v) {
    uint4 o;
    o.x = (u32)f2bf(v[0]) | ((u32)f2bf(v[1]) << 16);
    o.y = (u32)f2bf(v[2]) | ((u32)f2bf(v[3]) << 16);
    o.z = (u32)f2bf(v[4]) | ((u32)f2bf(v[5]) << 16);
    o.w = (u32)f2bf(v[6]) | ((u32)f2bf(v[7]) << 16);
    *(uint4*)p = o;
}
__device__ __forceinline__ uint4 cvt8_f32_bf16(const float* p) {
    float4 a = *(const float4*)p, b = *(const float4*)(p + 4);
    uint4 o;
    o.x = (u32)f2bf(a.x) | ((u32)f2bf(a.y) << 16);
    o.y = (u32)f2bf(a.z) | ((u32)f2bf(a.w) << 16);
    o.z = (u32)f2bf(b.x) | ((u32)f2bf(b.y) << 16);
    o.w = (u32)f2bf(b.z) | ((u32)f2bf(b.w) << 16);
    return o;
}
__device__ __forceinline__ void gload_lds16(const void* g, void* l) {
    __builtin_amdgcn_global_load_lds((const __attribute__((address_space(1))) u32*)g,
                                     (__attribute__((address_space(3))) u32*)l, 16, 0, 0);
}

// ---------------- weight f32 -> bf16 (8 elems/thread) ----------------
__global__ __launch_bounds__(256)
void cvt_w(const float* __restrict__ S, u16* __restrict__ D) {
    size_t i = ((size_t)blockIdx.x * 256 + threadIdx.x) * 8;
    *(uint4*)(D + i) = cvt8_f32_bf16(S + i);
}

// ---------------- RMSNorm (f32 in, bf16 out): one block per row of 2048 ----------------
__global__ __launch_bounds__(256)
void rmsnorm_k(const float* __restrict__ X, const float* __restrict__ W, u16* __restrict__ O) {
    const int row = blockIdx.x, tid = threadIdx.x;
    float v[8];
    load8f32(X + (size_t)row * DM + tid * 8, v);
    float ssq = 0.f;
#pragma unroll
    for (int i = 0; i < 8; ++i) ssq += v[i] * v[i];
#pragma unroll
    for (int d = 1; d < 64; d <<= 1) ssq += __shfl_xor(ssq, d);
    __shared__ float red[4];
    if ((tid & 63) == 0) red[tid >> 6] = ssq;
    __syncthreads();
    ssq = red[0] + red[1] + red[2] + red[3];
    const float inv = rsqrtf(ssq * (1.f / DM) + EPSF);
    float wv[8], o[8];
    load8f32(W + tid * 8, wv);
#pragma unroll
    for (int i = 0; i < 8; ++i) o[i] = v[i] * inv * wv[i];
    store8bf(O + (size_t)row * DM + tid * 8, o);
}

// ---------------- GEMM C[M,N] = A[M,K](bf16, lda=K) * Bw[N,K](bf16, row-stride ldb)^T ----
// m97 pattern: global_load_lds width-16 staging, XOR-swizzled LDS, 128x128 tile, BK=32.
// EPI: 0 = bf16 out, 1 = relu^2 bf16 out, 2 = + f32 Res -> f32 out
template<int EPI>
__global__ __launch_bounds__(256)
void gemm_bt(const u16* __restrict__ A, const u16* __restrict__ Bw,
             const float* __restrict__ Res, void* __restrict__ Cp,
             int M, int N, int K, int ldb) {
    __shared__ alignas(16) u16 As[128 * 32];
    __shared__ alignas(16) u16 Bs[128 * 32];
    const int tid = threadIdx.x;
    const int lane = tid & 63, w = tid >> 6;
    const int quad = lane >> 4, col = lane & 15;
    const int n0 = blockIdx.x * 128, m0 = blockIdx.y * 128;
    const int wm = (w >> 1) * 64, wn = (w & 1) * 64;

    // staging: 512 chunks of 8 elems per tile, 2 per thread; LDS slot s of row r
    // holds global chunk q = s ^ ((r>>1)&3)
    const int c0 = tid, c1 = tid + 256;
    const int ar0 = c0 >> 2, aq0 = (c0 & 3) ^ ((ar0 >> 1) & 3);
    const int ar1 = c1 >> 2, aq1 = (c1 & 3) ^ ((ar1 >> 1) & 3);
    const u16* agp0 = A  + (size_t)(m0 + ar0) * K + aq0 * 8;
    const u16* agp1 = A  + (size_t)(m0 + ar1) * K + aq1 * 8;
    const u16* bgp0 = Bw + (size_t)(n0 + ar0) * ldb + aq0 * 8;
    const u16* bgp1 = Bw + (size_t)(n0 + ar1) * ldb + aq1 * 8;
    u16* al0 = As + c0 * 8; u16* al1 = As + c1 * 8;
    u16* bl0 = Bs + c0 * 8; u16* bl1 = Bs + c1 * 8;

    int aoff[4], boff[4];
#pragma unroll
    for (int i = 0; i < 4; ++i) {
        int r = wm + i * 16 + col;
        aoff[i] = r * 32 + (quad ^ ((r >> 1) & 3)) * 8;
        r = wn + i * 16 + col;
        boff[i] = r * 32 + (quad ^ ((r >> 1) & 3)) * 8;
    }

    f32x4 acc[4][4];
#pragma unroll
    for (int i = 0; i < 4; ++i)
#pragma unroll
        for (int j = 0; j < 4; ++j) acc[i][j] = (f32x4){0.f, 0.f, 0.f, 0.f};

    for (int kt = 0; kt < K; kt += 32) {
        __syncthreads();
        gload_lds16(agp0 + kt, al0);
        gload_lds16(agp1 + kt, al1);
        gload_lds16(bgp0 + kt, bl0);
        gload_lds16(bgp1 + kt, bl1);
        __syncthreads();
        short8 af[4], bfr[4];
#pragma unroll
        for (int i = 0; i < 4; ++i) af[i] = *(const short8*)(As + aoff[i]);
#pragma unroll
        for (int i = 0; i < 4; ++i) bfr[i] = *(const short8*)(Bs + boff[i]);
#pragma unroll
        for (int mi = 0; mi < 4; ++mi)
#pragma unroll
            for (int ni = 0; ni < 4; ++ni)
                acc[mi][ni] = __builtin_amdgcn_mfma_f32_16x16x32_bf16(af[mi], bfr[ni], acc[mi][ni], 0, 0, 0);
    }

#pragma unroll
    for (int mi = 0; mi < 4; ++mi)
#pragma unroll
        for (int ni = 0; ni < 4; ++ni) {
            const int rbase = m0 + wm + mi * 16 + quad * 4;
            const int cc = n0 + wn + ni * 16 + col;
#pragma unroll
            for (int rr = 0; rr < 4; ++rr) {
                float v = acc[mi][ni][rr];
                size_t idx = (size_t)(rbase + rr) * N + cc;
                if (EPI == 0) ((u16*)Cp)[idx] = f2bf(v);
                else if (EPI == 1) { float t = fmaxf(v, 0.f); ((u16*)Cp)[idx] = f2bf(t * t); }
                else ((float*)Cp)[idx] = v + Res[idx];
            }
        }
}

// ---------------- RoPE + per-head RMSNorm on q,k; split v ----------------
__global__ __launch_bounds__(256)
void rope_split_k(const u16* __restrict__ QKV, const float* __restrict__ RC,
                  const float* __restrict__ QW, const float* __restrict__ KW,
                  u16* __restrict__ Qo, u16* __restrict__ Ko, u16* __restrict__ Vo) {
    const int row = blockIdx.x;                 // b*T + t
    const int t = row & (TT - 1), b = row >> 11;
    const int tid = threadIdx.x, h = tid >> 4, j = tid & 15;
    const size_t qb = (size_t)row * (3 * DM) + h * HD + j * 8;
    float q[8], k[8], cs[8], sn[8];
    load8f(QKV + qb, q);
    load8f(QKV + qb + DM, k);
    uint4 vv = *(const uint4*)(QKV + qb + 2 * DM);
    load8f32(RC + (size_t)t * HD + j * 8, cs);
    load8f32(RC + (size_t)(TT + t) * HD + j * 8, sn);
    float qr[8], kr[8];
#pragma unroll
    for (int p = 0; p < 4; ++p) {
        float c = cs[2 * p], s = sn[2 * p];
        qr[2*p]   = q[2*p]   * c - q[2*p+1] * s;
        qr[2*p+1] = q[2*p+1] * c + q[2*p]   * s;
        kr[2*p]   = k[2*p]   * c - k[2*p+1] * s;
        kr[2*p+1] = k[2*p+1] * c + k[2*p]   * s;
    }
    float sq = 0.f, sk = 0.f;
#pragma unroll
    for (int i = 0; i < 8; ++i) { sq += qr[i] * qr[i]; sk += kr[i] * kr[i]; }
#pragma unroll
    for (int d = 1; d < 16; d <<= 1) { sq += __shfl_xor(sq, d); sk += __shfl_xor(sk, d); }
    const float iq = rsqrtf(sq * (1.f / HD) + EPSF);
    const float ik = rsqrtf(sk * (1.f / HD) + EPSF);
    float qw[8], kw[8], oq[8], ok[8];
    load8f32(QW + j * 8, qw); load8f32(KW + j * 8, kw);
#pragma unroll
    for (int i = 0; i < 8; ++i) { oq[i] = qr[i] * iq * qw[i]; ok[i] = kr[i] * ik * kw[i]; }
    const size_t ob = ((size_t)(b * NH + h) * TT + t) * HD + j * 8;
    store8bf(Qo + ob, oq);
    store8bf(Ko + ob, ok);
    *(uint4*)(Vo + ob) = vv;
}

// ---------------- V transpose: [bh][T][128] -> [bh][128][T] ----------------
__global__ __launch_bounds__(256)
void transpose_v(const u16* __restrict__ V, u16* __restrict__ Vt) {
    __shared__ alignas(16) u16 tile[64][72];
    const int bh = blockIdx.z;
    const int t0 = blockIdx.x * 64, d0 = blockIdx.y * 64;
    const int tid = threadIdx.x;
#pragma unroll
    for (int i = 0; i < 2; ++i) {
        int c = i * 256 + tid;
        int r = c >> 3, cc = (c & 7) * 8;
        *(uint4*)(&tile[r][cc]) = *(const uint4*)(V + ((size_t)bh * TT + t0 + r) * HD + d0 + cc);
    }
    __syncthreads();
#pragma unroll
    for (int i = 0; i < 2; ++i) {
        int c = i * 256 + tid;
        int dc = c >> 3, rr = (c & 7) * 8;
        u16 tmp[8];
#pragma unroll
        for (int kk = 0; kk < 8; ++kk) tmp[kk] = tile[rr + kk][dc];
        uint4 o;
        o.x = (u32)tmp[0] | ((u32)tmp[1] << 16);
        o.y = (u32)tmp[2] | ((u32)tmp[3] << 16);
        o.z = (u32)tmp[4] | ((u32)tmp[5] << 16);
        o.w = (u32)tmp[6] | ((u32)tmp[7] << 16);
        *(uint4*)(Vt + ((size_t)bh * HD + d0 + dc) * TT + t0 + rr) = o;
    }
}

// ---------------- Causal flash attention, 64-query tile per block ----------------
__global__ __launch_bounds__(256)
void attn_k(const u16* __restrict__ Q, const u16* __restrict__ Kg,
            const u16* __restrict__ Vt, u16* __restrict__ O) {
    __shared__ alignas(16) u16 k_lds[64 * 128];
    __shared__ alignas(16) u16 v_lds[128 * 64];
    __shared__ alignas(16) u16 p_lds[4 * 16 * 72];
    const int qt = gridDim.x - 1 - blockIdx.x;   // long blocks first
    const int bh = blockIdx.y;
    const int tid = threadIdx.x, lane = tid & 63, w = tid >> 6;
    const int quad = lane >> 4, col = lane & 15;
    const int qbase = qt * 64;
    const int qrow = qbase + w * 16 + col;

    short8 qf[4];
    const u16* qp = Q + ((size_t)bh * TT + qrow) * HD;
#pragma unroll
    for (int s = 0; s < 4; ++s) qf[s] = *(const short8*)(qp + s * 32 + quad * 8);

    f32x4 oacc[8];
#pragma unroll
    for (int i = 0; i < 8; ++i) oacc[i] = (f32x4){0.f, 0.f, 0.f, 0.f};
    float mrow[4] = {NEGBIG, NEGBIG, NEGBIG, NEGBIG};
    float lrow[4] = {0.f, 0.f, 0.f, 0.f};
    const float scale = 0.08838834764831845f;   // 1/sqrt(128)

    for (int kt = 0; kt <= qt; ++kt) {
        const int kb = kt * 64;
        uint4 kreg[4], vreg[4];
#pragma unroll
        for (int i = 0; i < 4; ++i) {     // K tile: 64 rows x 16 chunks
            int lin = i * 256 + tid;
            int r = lin >> 4, sl = lin & 15;
            int gq = sl ^ (r & 15);
            kreg[i] = *(const uint4*)(Kg + ((size_t)bh * TT + kb + r) * HD + gq * 8);
        }
#pragma unroll
        for (int i = 0; i < 4; ++i) {     // Vt tile: 128 rows x 8 chunks
            int lin = i * 256 + tid;
            int r = lin >> 3, sl = lin & 7;
            int gq = sl ^ (r & 7);
            vreg[i] = *(const uint4*)(Vt + ((size_t)bh * HD + r) * TT + kb + gq * 8);
        }
        __syncthreads();
#pragma unroll
        for (int i = 0; i < 4; ++i) *(uint4*)(k_lds + (i * 256 + tid) * 8) = kreg[i];
#pragma unroll
        for (int i = 0; i < 4; ++i) *(uint4*)(v_lds + (i * 256 + tid) * 8) = vreg[i];
        __syncthreads();

        f32x4 sfr[4];
#pragma unroll
        for (int ni = 0; ni < 4; ++ni) sfr[ni] = (f32x4){0.f, 0.f, 0.f, 0.f};
#pragma unroll
        for (int ni = 0; ni < 4; ++ni) {
            const int r = ni * 16 + col;
#pragma unroll
            for (int s = 0; s < 4; ++s) {
                int sl = (s * 4 + quad) ^ (r & 15);
                short8 kf = *(const short8*)(k_lds + r * 128 + sl * 8);
                sfr[ni] = __builtin_amdgcn_mfma_f32_16x16x32_bf16(qf[s], kf, sfr[ni], 0, 0, 0);
            }
        }
        const bool diag = (kt == qt);
#pragma unroll
        for (int ni = 0; ni < 4; ++ni) {
            const int key = kb + ni * 16 + col;
#pragma unroll
            for (int rr = 0; rr < 4; ++rr) {
                float v = sfr[ni][rr] * scale;
                int qv = qbase + w * 16 + quad * 4 + rr;
                if (diag && key > qv) v = NEGBIG;
                sfr[ni][rr] = v;
            }
        }
        float mx[4];
#pragma unroll
        for (int rr = 0; rr < 4; ++rr)
            mx[rr] = fmaxf(fmaxf(sfr[0][rr], sfr[1][rr]), fmaxf(sfr[2][rr], sfr[3][rr]));
#pragma unroll
        for (int d = 1; d < 16; d <<= 1)
#pragma unroll
            for (int rr = 0; rr < 4; ++rr) mx[rr] = fmaxf(mx[rr], __shfl_xor(mx[rr], d));
        float alpha[4], rs[4];
#pragma unroll
        for (int rr = 0; rr < 4; ++rr) {
            float mn = fmaxf(mrow[rr], mx[rr]);
            alpha[rr] = __expf(mrow[rr] - mn);
            mrow[rr] = mn;
            rs[rr] = 0.f;
        }
#pragma unroll
        for (int ni = 0; ni < 4; ++ni)
#pragma unroll
            for (int rr = 0; rr < 4; ++rr) {
                float p = __expf(sfr[ni][rr] - mrow[rr]);
                sfr[ni][rr] = p;
                rs[rr] += p;
            }
#pragma unroll
        for (int d = 1; d < 16; d <<= 1)
#pragma unroll
            for (int rr = 0; rr < 4; ++rr) rs[rr] += __shfl_xor(rs[rr], d);
#pragma unroll
        for (int rr = 0; rr < 4; ++rr) lrow[rr] = lrow[rr] * alpha[rr] + rs[rr];
#pragma unroll
        for (int i = 0; i < 8; ++i)
#pragma unroll
            for (int rr = 0; rr < 4; ++rr) oacc[i][rr] *= alpha[rr];
        // P (C-layout) -> LDS -> A-layout
#pragma unroll
        for (int ni = 0; ni < 4; ++ni)
#pragma unroll
            for (int rr = 0; rr < 4; ++rr)
                p_lds[(w * 16 + quad * 4 + rr) * 72 + ni * 16 + col] = f2bf(sfr[ni][rr]);
#pragma unroll
        for (int ks = 0; ks < 2; ++ks) {
            short8 pa = *(const short8*)(p_lds + (w * 16 + col) * 72 + ks * 32 + quad * 8);
#pragma unroll
            for (int di = 0; di < 8; ++di) {
                int r = di * 16 + col;
                int sl = (ks * 4 + quad) ^ (r & 7);
                short8 vb = *(const short8*)(v_lds + r * 64 + sl * 8);
                oacc[di] = __builtin_amdgcn_mfma_f32_16x16x32_bf16(pa, vb, oacc[di], 0, 0, 0);
            }
        }
    }
    const int b = bh >> 4, h = bh & 15;
#pragma unroll
    for (int di = 0; di < 8; ++di)
#pragma unroll
        for (int rr = 0; rr < 4; ++rr) {
            int trow = qbase + w * 16 + quad * 4 + rr;
            float ov = oacc[di][rr] / lrow[rr];
            O[((size_t)(b * TT + trow)) * DM + h * HD + di * 16 + col] = f2bf(ov);
        }
}

extern "C" void kernel_launch(void* const* d_in, const int* in_sizes, int n_in,
                              void* d_out, int out_size, void* d_ws, size_t ws_size,
                              hipStream_t stream) {
    const float* x    = (const float*)d_in[0];
    const float* rc   = (const float*)d_in[1];
    const float* anw  = (const float*)d_in[2];
    const float* qkvw = (const float*)d_in[3];
    const float* qnw  = (const float*)d_in[4];
    const float* knw  = (const float*)d_in[5];
    const float* opw  = (const float*)d_in[6];
    const float* mnw  = (const float*)d_in[7];
    const float* miw  = (const float*)d_in[8];
    const float* mow  = (const float*)d_in[9];

    char* ws = (char*)d_ws;
    // Workspace plan, 120 MiB peak (MiB offsets). Late-phase owners:
    //   hbuf[0,16) Wmi[16,48) Wmo[48,80) mbuf[80,112) Wo[112,120)
    // Early/mid aliases (dead before late owner is written):
    //   Wq[16,40)  qkv[48,96)  qh[96,112)  kh[112,128)  vh[0,16)  vt[16,32)  aout[32,48)
    // Residual x2 lives in d_out (f32), accumulated by the mlp_out halves.
    u16* hbuf = (u16*)(ws);
    u16* Wq   = (u16*)(ws + (16ll  << 20));
    u16* Wmi  = (u16*)(ws + (16ll  << 20));
    u16* vt   = (u16*)(ws + (16ll  << 20));
    u16* aout = (u16*)(ws + (32ll  << 20));
    u16* Wmo  = (u16*)(ws + (48ll  << 20));
    u16* qkv  = (u16*)(ws + (48ll  << 20));
    u16* mbuf = (u16*)(ws + (80ll  << 20));
    u16* qh   = (u16*)(ws + (96ll  << 20));
    u16* Wo   = (u16*)(ws + (112ll << 20));
    u16* kh   = (u16*)(ws + (112ll << 20));
    u16* vh   = (u16*)(ws);
    float* xo = (float*)d_out;

    rmsnorm_k<<<MR, 256, 0, stream>>>(x, anw, hbuf);
    cvt_w<<<6144, 256, 0, stream>>>(qkvw, Wq);                     // 3DM*DM
    gemm_bt<0><<<dim3(48, 32), 256, 0, stream>>>(hbuf, Wq, nullptr, qkv, MR, 3 * DM, DM, DM);
    rope_split_k<<<MR, 256, 0, stream>>>(qkv, rc, qnw, knw, qh, kh, vh);
    transpose_v<<<dim3(32, 2, 32), 256, 0, stream>>>(vh, vt);
    attn_k<<<dim3(32, 32), 256, 0, stream>>>(qh, kh, vt, aout);
    cvt_w<<<2048, 256, 0, stream>>>(opw, Wo);                      // DM*DM (kh dead)
    cvt_w<<<8192, 256, 0, stream>>>(mow, Wmo);                     // DM*FFN (qkv dead)
    gemm_bt<2><<<dim3(16, 32), 256, 0, stream>>>(aout, Wo, x, xo, MR, DM, DM, DM);
    rmsnorm_k<<<MR, 256, 0, stream>>>(xo, mnw, hbuf);
    cvt_w<<<8192, 256, 0, stream>>>(miw, Wmi);                     // FFN*DM (vt/aout dead)
    // MLP in two FFN halves; mbuf is 4096x4096 bf16, d_out accumulates in f32.
    gemm_bt<1><<<dim3(32, 32), 256, 0, stream>>>(hbuf, Wmi, nullptr, mbuf, MR, FFN / 2, DM, DM);
    gemm_bt<2><<<dim3(16, 32), 256, 0, stream>>>(mbuf, Wmo, xo, xo, MR, DM, FFN / 2, FFN);
    gemm_bt<1><<<dim3(32, 32), 256, 0, stream>>>(hbuf, Wmi + (size_t)(FFN / 2) * DM, nullptr, mbuf, MR, FFN / 2, DM, DM);
    gemm_bt<2><<<dim3(16, 32), 256, 0, stream>>>(mbuf, Wmo + FFN / 2, xo, xo, MR, DM, FFN / 2, FFN);
}